// Round 7
// baseline (385.346 us; speedup 1.0000x reference)
//
#include <hip/hip_runtime.h>
#include <hip/hip_bf16.h>

// Problem constants (fixed by reference setup_inputs)
constexpr int NN   = 50000;    // nodes
constexpr int NE   = 600000;   // edges
constexpr int NRBF = 50;       // rbf features
constexpr int DIM  = 128;      // embedding dim
constexpr float CUT = 5.0f;
constexpr float PI_F = 3.14159265358979323846f;

constexpr int CAP  = 32;       // bucket capacity (active degree ~Poisson(9.2); ovf fallback)
constexpr int SPAN = 12;       // nodes per wave (4168 waves = 16/CU, all co-resident)

// Workspace layout (byte offsets). Total ~41.1 MB.
constexpr size_t OFF_DEG   = 0;                                 // [NN] int
constexpr size_t OFF_OVFC  = (size_t)NN * 4;                    // [1] int (memset covers both)
constexpr size_t OFF_EBUF  = 200960;                            // [NN*CAP] int4 (25.6 MB), 16-B aligned
constexpr size_t OFF_OVF   = OFF_EBUF + (size_t)NN * CAP * 16;  // [NE] int (2.4 MB)
constexpr size_t OFF_WAUG  = OFF_OVF  + (size_t)NE * 4;         // [128*64] bf16 (16 KB)
constexpr size_t OFF_EPERM = OFF_WAUG + 128 * 64 * 2;           // [100*128] bf16 permuted (25.6 KB)
constexpr size_t OFF_XI    = OFF_EPERM + 100 * 128 * 2;         // [NN*128] bf16 normal order (12.8 MB)

// emb_perm PERMUTED layout: position p holds dim delta(p) = 16*(p&7) + (p>>3).
// Lane c's positions 8c..8c+7 <-> dims {16q + c} = exactly its MFMA-D column across nt.

typedef __attribute__((ext_vector_type(4))) float f32x4;
typedef __attribute__((ext_vector_type(8))) short short8;

__device__ __forceinline__ float bf2f(unsigned short u) {
    return __uint_as_float(((unsigned int)u) << 16);
}
__device__ __forceinline__ unsigned short f2bf(float f) {
    return __bfloat16_as_ushort(__float2bfloat16(f));
}

// ---------------------------------------------------------------------------
// Kernel 1 (MERGED prep_w + build_buckets): bucket active edges by dst with a
// single packed int4 store per edge; low tids additionally emit W_aug/emb_perm.
// ---------------------------------------------------------------------------
__global__ __launch_bounds__(256)
void bucket_prep(const int* __restrict__ dst, const float* __restrict__ dist,
                 const int* __restrict__ src, const int* __restrict__ node_type,
                 int* __restrict__ deg, int4* __restrict__ ebuf,
                 int* __restrict__ ovf, int* __restrict__ ovf_cnt,
                 const float* __restrict__ W_e, const float* __restrict__ b_e,
                 const float* __restrict__ emb,
                 unsigned short* __restrict__ W_aug, unsigned short* __restrict__ emb_perm)
{
    const int e = blockIdx.x * 256 + threadIdx.x;

    if (e < NE) {
        const float dd = dist[e];
        if (dd < CUT) {
            const float w = 0.5f * (__cosf(dd * (PI_F / CUT)) + 1.0f);
            const int n = dst[e];
            const int pos = atomicAdd(&deg[n], 1);
            if (pos < CAP) {
                ebuf[(size_t)n * CAP + pos] =
                    make_int4(e, __float_as_int(w), node_type[src[e]], 0);
            } else {
                ovf[atomicAdd(ovf_cnt, 1)] = e;
            }
        }
    }

    // prep_w work, folded in (first 82 blocks' tids)
    if (e < 128 * 64) {
        const int d = e >> 6, k = e & 63;
        float v = 0.0f;
        if (k < NRBF)       v = W_e[d * NRBF + k];
        else if (k == NRBF) v = b_e[d];
        W_aug[e] = f2bf(v);
    } else if (e < 128 * 64 + 100 * 128) {
        const int i = e - 128 * 64;
        const int tau = i >> 7, p = i & 127;
        const int d = 16 * (p & 7) + (p >> 3);
        emb_perm[i] = f2bf(emb[tau * DIM + d]);
    }
}

// ---------------------------------------------------------------------------
// Fused gather helpers. Arithmetic is BIT-IDENTICAL to the proven R4/R6 path.
// Bucket metadata is read DIRECTLY from global (contiguous 512-B row per node,
// L1/L2-hot; reads only the active slots — undoes R6's +6 MB ebuf over-read).
// ---------------------------------------------------------------------------
struct NodeLoad {
    float2 r0, r1, r2, r3, q0, q1, q2, q3;   // raw rbf float2s for round 0
    float  ccl;
    int    degn;
};

__device__ __forceinline__ void issue_node(const int4* __restrict__ ebn, int dn,
                                           const float* __restrict__ rbf,
                                           int c, int g, NodeLoad& L)
{
    L.degn = dn < CAP ? dn : CAP;
    int ea = 0; L.ccl = 0.0f;
    if (c < L.degn) {                         // round-0 slot = c
        const int4 eb = ebn[c];
        ea    = eb.x;
        L.ccl = __int_as_float(eb.y);
    }
    const float2* rp2 = (const float2*)(rbf + (size_t)ea * NRBF);  // ea=0 inactive: safe
    L.r0 = rp2[4 * g];     L.r1 = rp2[4 * g + 1];
    L.r2 = rp2[4 * g + 2]; L.r3 = rp2[4 * g + 3];
    L.q0 = make_float2(0.f, 0.f); L.q1 = L.q0; L.q2 = L.q0; L.q3 = L.q0;
    if (g < 2) {
        L.q0 = rp2[16 + 4 * g]; L.q1 = rp2[17 + 4 * g];
        L.q2 = rp2[18 + 4 * g]; L.q3 = rp2[19 + 4 * g];
    } else if (g == 2) {
        L.q0 = rp2[24];                        // k48,k49
    }
}

__device__ __forceinline__ void round_compute(
    float ccl, float2 r0, float2 r1, float2 r2, float2 r3,
    float2 q0, float2 q1, float2 q2, float2 q3,
    int j0, int degn, int c, int g,
    const unsigned short* __restrict__ wlds, const int4* __restrict__ ebn,
    const unsigned short* __restrict__ emb_perm, float v[8])
{
    short8 a0, a1;
    a0[0] = (short)f2bf(ccl * r0.x); a0[1] = (short)f2bf(ccl * r0.y);
    a0[2] = (short)f2bf(ccl * r1.x); a0[3] = (short)f2bf(ccl * r1.y);
    a0[4] = (short)f2bf(ccl * r2.x); a0[5] = (short)f2bf(ccl * r2.y);
    a0[6] = (short)f2bf(ccl * r3.x); a0[7] = (short)f2bf(ccl * r3.y);
    a1[0] = (short)f2bf(ccl * q0.x); a1[1] = (short)f2bf(ccl * q0.y);
    a1[2] = (short)f2bf(ccl * q1.x); a1[3] = (short)f2bf(ccl * q1.y);
    a1[4] = (short)f2bf(ccl * q2.x); a1[5] = (short)f2bf(ccl * q2.y);
    a1[6] = (short)f2bf(ccl * q3.x); a1[7] = (short)f2bf(ccl * q3.y);
    if (g == 2) {                              // k50 = cc (b_e hook), k51+ = 0
        a1[2] = (short)f2bf(ccl);
        a1[3] = 0; a1[4] = 0; a1[5] = 0; a1[6] = 0; a1[7] = 0;
    }

    f32x4 acc[8] = {};
    #pragma unroll
    for (int nt = 0; nt < 8; ++nt) {
        const short8 bf0 = *(const short8*)((const char*)wlds + (nt * 16 + c) * 144 + g * 16);
        acc[nt] = __builtin_amdgcn_mfma_f32_16x16x32_bf16(a0, bf0, acc[nt], 0, 0, 0);
    }
    #pragma unroll
    for (int nt = 0; nt < 8; ++nt) {
        const short8 bf1 = *(const short8*)((const char*)wlds + (nt * 16 + c) * 144 + (4 + g) * 16);
        acc[nt] = __builtin_amdgcn_mfma_f32_16x16x32_bf16(a1, bf1, acc[nt], 0, 0, 0);
    }

    #pragma unroll
    for (int r = 0; r < 4; ++r) {
        const int jr = j0 + 4 * g + r;
        if (jr < degn) {
            const int rw = ((const int*)&ebn[jr])[2];      // tau (uniform per r, L1-hot)
            const int4 em = *(const int4*)(emb_perm + rw * DIM + 8 * c);
            const unsigned int* ep = (const unsigned int*)&em;
            #pragma unroll
            for (int q = 0; q < 4; ++q) {
                const float m0 = bf2f((unsigned short)(ep[q] & 0xffff));
                const float m1 = bf2f((unsigned short)(ep[q] >> 16));
                v[2 * q]     += bf2f(f2bf(acc[2 * q][r]     * m0));   // bf16-round: bit-
                v[2 * q + 1] += bf2f(f2bf(acc[2 * q + 1][r] * m1));   // identical to msg path
            }
        }
    }
}

__device__ __forceinline__ void compute_node(
    const NodeLoad& L, const int4* __restrict__ ebn, int c, int g,
    const unsigned short* __restrict__ wlds,
    const unsigned short* __restrict__ emb_perm, const float* __restrict__ rbf,
    float v[8])
{
    round_compute(L.ccl, L.r0, L.r1, L.r2, L.r3, L.q0, L.q1, L.q2, L.q3,
                  0, L.degn, c, g, wlds, ebn, emb_perm, v);
    if (L.degn > 16) {                         // rare (P ~ 1%): round 1, slots 16..31
        int ea = 0; float ccl = 0.0f;
        const int slot = 16 + c;
        if (slot < L.degn) {
            const int4 eb = ebn[slot];
            ea  = eb.x;
            ccl = __int_as_float(eb.y);
        }
        const float2* rp2 = (const float2*)(rbf + (size_t)ea * NRBF);
        const float2 r0 = rp2[4 * g],     r1 = rp2[4 * g + 1];
        const float2 r2 = rp2[4 * g + 2], r3 = rp2[4 * g + 3];
        float2 q0 = make_float2(0.f, 0.f), q1 = q0, q2 = q0, q3 = q0;
        if (g < 2) {
            q0 = rp2[16 + 4 * g]; q1 = rp2[17 + 4 * g];
            q2 = rp2[18 + 4 * g]; q3 = rp2[19 + 4 * g];
        } else if (g == 2) {
            q0 = rp2[24];
        }
        round_compute(ccl, r0, r1, r2, r3, q0, q1, q2, q3,
                      16, L.degn, c, g, wlds, ebn, emb_perm, v);
    }
}

__device__ __forceinline__ void finish_node(
    float v[8], int n, int c, int g, int ocnt,
    const int* __restrict__ ovf, const int* __restrict__ dst,
    const float* __restrict__ dist, const int* __restrict__ src,
    const int* __restrict__ node_type, const float* __restrict__ rbf,
    const unsigned short* __restrict__ W_aug_g,
    const unsigned short* __restrict__ emb_perm, unsigned short* __restrict__ xi)
{
    // Overflow fallback (deg > CAP): essentially never taken, kept for correctness.
    for (int j = 0; j < ocnt; ++j) {
        const int e = ovf[j];
        if (dst[e] != n) continue;
        const float dd  = dist[e];
        const float ccl = 0.5f * (__cosf(dd * (PI_F / CUT)) + 1.0f);
        if (g == 0) {
            const int tau = node_type[src[e]];
            const float* rp = rbf + (size_t)e * NRBF;
            const float ccb16 = bf2f(f2bf(ccl));
            #pragma unroll
            for (int q = 0; q < 8; ++q) {
                const int d = 16 * q + c;
                float s = bf2f(W_aug_g[d * 64 + NRBF]) * ccb16;       // b_e * cc
                for (int k = 0; k < NRBF; ++k)
                    s += bf2f(W_aug_g[d * 64 + k]) * bf2f(f2bf(ccl * rp[k]));
                v[q] += bf2f(f2bf(s * bf2f(emb_perm[tau * DIM + 8 * c + q])));
            }
        }
    }

    #pragma unroll
    for (int q = 0; q < 8; ++q) {
        v[q] += __shfl_xor(v[q], 16);
        v[q] += __shfl_xor(v[q], 32);
    }

    float s0 = v[0], s1 = v[1];
    if (g == 1)      { s0 = v[2]; s1 = v[3]; }
    else if (g == 2) { s0 = v[4]; s1 = v[5]; }
    else if (g == 3) { s0 = v[6]; s1 = v[7]; }
    xi[(size_t)n * DIM + 32 * g + c]      = f2bf(s0);
    xi[(size_t)n * DIM + 32 * g + 16 + c] = f2bf(s1);
}

// ---------------------------------------------------------------------------
// Kernel 2 (FUSED edge_msg + gather_sum, v5 — fully persistent waves).
//
// R6 post-mortem: 128 us, still latency-bound — 6250 SHORT blocks each paid an
// 18-KB wlds stage + barrier for 8 nodes, then died (occupancy 20%, dispatch
// churn). Resource math: VGPR~88 (5 waves/SIMD) x LDS 18 KB -> 1042 blocks x 4
// waves = 4168 waves = 16/CU ALL CO-RESIDENT. v5: each wave owns a contiguous
// SPAN=12 node range; wlds staged ONCE per block; ONE barrier; then waves run
// free (no further sync). Bucket metadata read directly from global (L1/L2-hot
// contiguous row; only active slots — undoes R6's ebuf over-read).
// Per-pair dual-issue kept (ILP on top of the 16-wave TLP).
// ---------------------------------------------------------------------------
__global__ __launch_bounds__(256)
void gather_fused(const float* __restrict__ rbf,
                  const int* __restrict__ deg, const int4* __restrict__ ebuf,
                  const unsigned short* __restrict__ W_aug,
                  const unsigned short* __restrict__ emb_perm,
                  const int* __restrict__ ovf, const int* __restrict__ ovf_cnt,
                  const int* __restrict__ dst, const float* __restrict__ dist,
                  const int* __restrict__ src, const int* __restrict__ node_type,
                  unsigned short* __restrict__ xi)
{
    // W_aug tile: 128 rows x 72 shorts (144-B padded rows; ~4% conflict cycles).
    __shared__ __align__(16) unsigned short wlds[128 * 72];   // 18 KB

    const int t = threadIdx.x, l = t & 63;
    const int wv = t >> 6;
    const int c = l & 15, g = l >> 4;

    // ---- stage W_aug once per block ----
    #pragma unroll
    for (int i = 0; i < 4; ++i) {
        const int ch = i * 256 + t;                // 1024 x 16-B chunks
        const int row = ch >> 3, f = ch & 7;
        *(int4*)((char*)wlds + row * 144 + f * 16) = ((const int4*)W_aug)[ch];
    }
    __syncthreads();

    const int nstart = (blockIdx.x * 4 + wv) * SPAN;
    if (nstart >= NN) return;
    const int nend = (nstart + SPAN < NN) ? nstart + SPAN : NN;
    const int ocnt = ovf_cnt[0];

    for (int n = nstart; n < nend; n += 2) {
        const bool has1 = (n + 1 < nend);
        const int4* ebn0 = ebuf + (size_t)n * CAP;
        const int4* ebn1 = ebuf + (size_t)(n + 1) * CAP;

        // Issue both nodes' scattered rbf loads up-front (dual register banks):
        // node1's round-trip hides under node0's MFMA/epilogue.
        NodeLoad L0, L1;
        issue_node(ebn0, deg[n], rbf, c, g, L0);
        if (has1) issue_node(ebn1, deg[n + 1], rbf, c, g, L1);

        {
            float v[8] = {};
            compute_node(L0, ebn0, c, g, wlds, emb_perm, rbf, v);
            finish_node(v, n, c, g, ocnt, ovf, dst, dist, src,
                        node_type, rbf, W_aug, emb_perm, xi);
        }
        if (has1) {
            float v[8] = {};
            compute_node(L1, ebn1, c, g, wlds, emb_perm, rbf, v);
            finish_node(v, n + 1, c, g, ocnt, ovf, dst, dist, src,
                        node_type, rbf, W_aug, emb_perm, xi);
        }
    }
}

// ---------------------------------------------------------------------------
// Kernel 3: out[n] = [x_nodes[n] | xi[n]] @ W_c^T + b_c  via bf16 MFMA.
// (unchanged — known good)
// ---------------------------------------------------------------------------
__global__ __launch_bounds__(256)
void combine_mfma(const float* __restrict__ x_nodes, const __hip_bfloat16* __restrict__ xi,
                  const float* __restrict__ W_c, const float* __restrict__ b_c,
                  float* __restrict__ out)
{
    __shared__ unsigned short As[64][72];
    __shared__ unsigned short Bs[128][72];

    const int t  = threadIdx.x;
    const int wv = t >> 6;
    const int l  = t & 63;
    const int n0 = blockIdx.x * 64;

    f32x4 acc[8] = {};

    for (int kc = 0; kc < 4; ++kc) {
        const int kb = kc * 64;
        if (kc) __syncthreads();
        {
            const int r  = t >> 2;
            const int c0 = (t & 3) * 16;
            const int n  = n0 + r;
            if (kc < 2) {
                float4 v[4];
                if (n < NN) {
                    const float4* p = (const float4*)(x_nodes + (size_t)n * DIM + kb + c0);
                    v[0] = p[0]; v[1] = p[1]; v[2] = p[2]; v[3] = p[3];
                } else {
                    v[0] = v[1] = v[2] = v[3] = make_float4(0.f, 0.f, 0.f, 0.f);
                }
                unsigned short* dp = &As[r][c0];
                #pragma unroll
                for (int q = 0; q < 4; ++q) {
                    *(ushort2*)&dp[q * 4]     = make_ushort2(f2bf(v[q].x), f2bf(v[q].y));
                    *(ushort2*)&dp[q * 4 + 2] = make_ushort2(f2bf(v[q].z), f2bf(v[q].w));
                }
            } else {
                int4 v0 = make_int4(0, 0, 0, 0), v1 = make_int4(0, 0, 0, 0);
                if (n < NN) {
                    const int4* p = (const int4*)(xi + (size_t)n * DIM + (kb - DIM) + c0);
                    v0 = p[0];
                    v1 = p[1];
                }
                *(int4*)&As[r][c0]     = v0;
                *(int4*)&As[r][c0 + 8] = v1;
            }
        }
        {
            const int dch = t >> 1;
            const int c0  = (t & 1) * 32;
            const float4* p = (const float4*)(W_c + (size_t)dch * (2 * DIM) + kb + c0);
            unsigned short* dp = &Bs[dch][c0];
            #pragma unroll
            for (int q = 0; q < 8; ++q) {
                const float4 v = p[q];
                *(ushort2*)&dp[q * 4]     = make_ushort2(f2bf(v.x), f2bf(v.y));
                *(ushort2*)&dp[q * 4 + 2] = make_ushort2(f2bf(v.z), f2bf(v.w));
            }
        }
        __syncthreads();
        #pragma unroll
        for (int s = 0; s < 2; ++s) {
            const int ko = s * 32 + (l >> 4) * 8;
            const short8 af = *(const short8*)&As[wv * 16 + (l & 15)][ko];
            #pragma unroll
            for (int nt = 0; nt < 8; ++nt) {
                const short8 bf = *(const short8*)&Bs[nt * 16 + (l & 15)][ko];
                acc[nt] = __builtin_amdgcn_mfma_f32_16x16x32_bf16(af, bf, acc[nt], 0, 0, 0);
            }
        }
    }

    const int col = l & 15;
    const int rq  = (l >> 4) * 4;
    #pragma unroll
    for (int nt = 0; nt < 8; ++nt) {
        const int dim = nt * 16 + col;
        const float bc = b_c[dim];
        #pragma unroll
        for (int r = 0; r < 4; ++r) {
            const int node = n0 + wv * 16 + rq + r;
            if (node < NN)
                out[(size_t)node * DIM + dim] = acc[nt][r] + bc;
        }
    }
}

// ---------------------------------------------------------------------------
extern "C" void kernel_launch(void* const* d_in, const int* in_sizes, int n_in,
                              void* d_out, int out_size, void* d_ws, size_t ws_size,
                              hipStream_t stream)
{
    const int*   node_type = (const int*)  d_in[0];
    const float* x_nodes   = (const float*)d_in[1];
    const int*   src       = (const int*)  d_in[2];
    const int*   dst       = (const int*)  d_in[3];
    const float* rbf       = (const float*)d_in[4];
    const float* dist      = (const float*)d_in[5];
    const float* emb       = (const float*)d_in[6];
    const float* W_e       = (const float*)d_in[7];
    const float* b_e       = (const float*)d_in[8];
    const float* W_c       = (const float*)d_in[9];
    const float* b_c       = (const float*)d_in[10];
    float* out = (float*)d_out;

    char* ws = (char*)d_ws;
    int*            deg      = (int*)(ws + OFF_DEG);
    int*            ovf_cnt  = (int*)(ws + OFF_OVFC);
    int4*           ebuf     = (int4*)(ws + OFF_EBUF);
    int*            ovf      = (int*)(ws + OFF_OVF);
    unsigned short* W_aug    = (unsigned short*)(ws + OFF_WAUG);
    unsigned short* emb_perm = (unsigned short*)(ws + OFF_EPERM);
    unsigned short* xi       = (unsigned short*)(ws + OFF_XI);

    hipMemsetAsync(deg, 0, (NN + 1) * sizeof(int), stream);

    bucket_prep<<<(NE + 255) / 256, 256, 0, stream>>>(
        dst, dist, src, node_type, deg, ebuf, ovf, ovf_cnt,
        W_e, b_e, emb, W_aug, emb_perm);

    // waves = ceil(NN/SPAN) = 4167; blocks = ceil(4167/4) = 1042 (all resident)
    gather_fused<<<(((NN + SPAN - 1) / SPAN) + 3) / 4, 256, 0, stream>>>(
        rbf, deg, ebuf, W_aug, emb_perm,
        ovf, ovf_cnt, dst, dist, src, node_type, xi);

    combine_mfma<<<(NN + 63) / 64, 256, 0, stream>>>(
        x_nodes, (const __hip_bfloat16*)xi, W_c, b_c, out);
}

// Round 8
// 360.949 us; speedup vs baseline: 1.0676x; 1.0676x over previous
//
#include <hip/hip_runtime.h>
#include <hip/hip_bf16.h>

// Problem constants (fixed by reference setup_inputs)
constexpr int NN   = 50000;    // nodes
constexpr int NE   = 600000;   // edges
constexpr int NRBF = 50;       // rbf features
constexpr int DIM  = 128;      // embedding dim
constexpr float CUT = 5.0f;
constexpr float PI_F = 3.14159265358979323846f;

constexpr int CAP = 32;        // bucket capacity (active degree ~Poisson(9.2); ovf fallback)

// Workspace layout (byte offsets). Total ~28.5 MB (xi eliminated by fusion).
constexpr size_t OFF_DEG   = 0;                                 // [NN] int
constexpr size_t OFF_OVFC  = (size_t)NN * 4;                    // [1] int (memset covers both)
constexpr size_t OFF_EBUF  = 200960;                            // [NN*CAP] int4 (25.6 MB), 16-B aligned
constexpr size_t OFF_OVF   = OFF_EBUF + (size_t)NN * CAP * 16;  // [NE] int (2.4 MB)
constexpr size_t OFF_WAUG  = OFF_OVF  + (size_t)NE * 4;         // [128*64] bf16 (16 KB)
constexpr size_t OFF_EPERM = OFF_WAUG + 128 * 64 * 2;           // [100*128] bf16 permuted (25.6 KB)
constexpr size_t OFF_WCB   = OFF_EPERM + 100 * 128 * 2;         // [128*256] bf16 W_c (64 KB)

// emb_perm PERMUTED layout: position p holds dim delta(p) = 16*(p&7) + (p>>3).
// Lane c's positions 8c..8c+7 <-> dims {16q + c} = exactly its MFMA-D column across nt.

typedef __attribute__((ext_vector_type(4))) float f32x4;
typedef __attribute__((ext_vector_type(8))) short short8;

__device__ __forceinline__ float bf2f(unsigned short u) {
    return __uint_as_float(((unsigned int)u) << 16);
}
__device__ __forceinline__ unsigned short f2bf(float f) {
    return __bfloat16_as_ushort(__float2bfloat16(f));
}

// ---------------------------------------------------------------------------
// Kernel 1 (MERGED prep_w + build_buckets + W_c cast): bucket active edges by
// dst (single packed int4 store per edge); low tids emit W_aug/emb_perm/W_cb.
// ---------------------------------------------------------------------------
__global__ __launch_bounds__(256)
void bucket_prep(const int* __restrict__ dst, const float* __restrict__ dist,
                 const int* __restrict__ src, const int* __restrict__ node_type,
                 int* __restrict__ deg, int4* __restrict__ ebuf,
                 int* __restrict__ ovf, int* __restrict__ ovf_cnt,
                 const float* __restrict__ W_e, const float* __restrict__ b_e,
                 const float* __restrict__ emb, const float* __restrict__ W_c,
                 unsigned short* __restrict__ W_aug, unsigned short* __restrict__ emb_perm,
                 unsigned short* __restrict__ W_cb)
{
    const int e = blockIdx.x * 256 + threadIdx.x;

    if (e < NE) {
        const float dd = dist[e];
        if (dd < CUT) {
            const float w = 0.5f * (__cosf(dd * (PI_F / CUT)) + 1.0f);
            const int n = dst[e];
            const int pos = atomicAdd(&deg[n], 1);
            if (pos < CAP) {
                ebuf[(size_t)n * CAP + pos] =
                    make_int4(e, __float_as_int(w), node_type[src[e]], 0);
            } else {
                ovf[atomicAdd(ovf_cnt, 1)] = e;
            }
        }
    }

    // small-weight prep, folded in (first 210 blocks' tids)
    if (e < 128 * 64) {
        const int d = e >> 6, k = e & 63;
        float v = 0.0f;
        if (k < NRBF)       v = W_e[d * NRBF + k];
        else if (k == NRBF) v = b_e[d];
        W_aug[e] = f2bf(v);
    } else if (e < 128 * 64 + 100 * 128) {
        const int i = e - 128 * 64;
        const int tau = i >> 7, p = i & 127;
        const int d = 16 * (p & 7) + (p >> 3);
        emb_perm[i] = f2bf(emb[tau * DIM + d]);
    } else if (e < 128 * 64 + 100 * 128 + 128 * 256) {
        const int i = e - (128 * 64 + 100 * 128);
        W_cb[i] = f2bf(W_c[i]);                    // row-major [128][256], same index
    }
}

// ---------------------------------------------------------------------------
// Fused gather helpers. Arithmetic is BIT-IDENTICAL to the proven R4/R6 path.
// ---------------------------------------------------------------------------
struct NodeLoad {
    float2 r0, r1, r2, r3, q0, q1, q2, q3;   // raw rbf float2s for round 0
    float  ccl;
    int    degn;
    int    mb;
};

__device__ __forceinline__ void issue_node(const int4* __restrict__ eb_s,
                                           const int* __restrict__ deg_s,
                                           const float* __restrict__ rbf,
                                           int nl, int c, int g, NodeLoad& L)
{
    const int dn = deg_s[nl];
    L.degn = dn < CAP ? dn : CAP;
    L.mb   = nl * 32;
    int ea = 0; L.ccl = 0.0f;
    if (c < L.degn) {                         // round-0 slot = c
        const int4 eb = eb_s[L.mb + c];
        ea    = eb.x;
        L.ccl = __int_as_float(eb.y);
    }
    const float2* rp2 = (const float2*)(rbf + (size_t)ea * NRBF);  // ea=0 inactive: safe
    L.r0 = rp2[4 * g];     L.r1 = rp2[4 * g + 1];
    L.r2 = rp2[4 * g + 2]; L.r3 = rp2[4 * g + 3];
    L.q0 = make_float2(0.f, 0.f); L.q1 = L.q0; L.q2 = L.q0; L.q3 = L.q0;
    if (g < 2) {
        L.q0 = rp2[16 + 4 * g]; L.q1 = rp2[17 + 4 * g];
        L.q2 = rp2[18 + 4 * g]; L.q3 = rp2[19 + 4 * g];
    } else if (g == 2) {
        L.q0 = rp2[24];                        // k48,k49
    }
}

__device__ __forceinline__ void round_compute(
    float ccl, float2 r0, float2 r1, float2 r2, float2 r3,
    float2 q0, float2 q1, float2 q2, float2 q3,
    int j0, int degn, int mb, int c, int g,
    const unsigned short* __restrict__ wlds, const int4* __restrict__ eb_s,
    const unsigned short* __restrict__ emb_perm, float v[8])
{
    short8 a0, a1;
    a0[0] = (short)f2bf(ccl * r0.x); a0[1] = (short)f2bf(ccl * r0.y);
    a0[2] = (short)f2bf(ccl * r1.x); a0[3] = (short)f2bf(ccl * r1.y);
    a0[4] = (short)f2bf(ccl * r2.x); a0[5] = (short)f2bf(ccl * r2.y);
    a0[6] = (short)f2bf(ccl * r3.x); a0[7] = (short)f2bf(ccl * r3.y);
    a1[0] = (short)f2bf(ccl * q0.x); a1[1] = (short)f2bf(ccl * q0.y);
    a1[2] = (short)f2bf(ccl * q1.x); a1[3] = (short)f2bf(ccl * q1.y);
    a1[4] = (short)f2bf(ccl * q2.x); a1[5] = (short)f2bf(ccl * q2.y);
    a1[6] = (short)f2bf(ccl * q3.x); a1[7] = (short)f2bf(ccl * q3.y);
    if (g == 2) {                              // k50 = cc (b_e hook), k51+ = 0
        a1[2] = (short)f2bf(ccl);
        a1[3] = 0; a1[4] = 0; a1[5] = 0; a1[6] = 0; a1[7] = 0;
    }

    f32x4 acc[8] = {};
    #pragma unroll
    for (int nt = 0; nt < 8; ++nt) {
        const short8 bf0 = *(const short8*)((const char*)wlds + (nt * 16 + c) * 144 + g * 16);
        acc[nt] = __builtin_amdgcn_mfma_f32_16x16x32_bf16(a0, bf0, acc[nt], 0, 0, 0);
    }
    #pragma unroll
    for (int nt = 0; nt < 8; ++nt) {
        const short8 bf1 = *(const short8*)((const char*)wlds + (nt * 16 + c) * 144 + (4 + g) * 16);
        acc[nt] = __builtin_amdgcn_mfma_f32_16x16x32_bf16(a1, bf1, acc[nt], 0, 0, 0);
    }

    #pragma unroll
    for (int r = 0; r < 4; ++r) {
        const int jr = j0 + 4 * g + r;
        if (jr < degn) {
            const int rw = ((const int*)&eb_s[mb + jr])[2];      // tau
            const int4 em = *(const int4*)(emb_perm + rw * DIM + 8 * c);
            const unsigned int* ep = (const unsigned int*)&em;
            #pragma unroll
            for (int q = 0; q < 4; ++q) {
                const float m0 = bf2f((unsigned short)(ep[q] & 0xffff));
                const float m1 = bf2f((unsigned short)(ep[q] >> 16));
                v[2 * q]     += bf2f(f2bf(acc[2 * q][r]     * m0));   // bf16-round: bit-
                v[2 * q + 1] += bf2f(f2bf(acc[2 * q + 1][r] * m1));   // identical to msg path
            }
        }
    }
}

__device__ __forceinline__ void compute_node(
    const NodeLoad& L, int c, int g,
    const unsigned short* __restrict__ wlds, const int4* __restrict__ eb_s,
    const unsigned short* __restrict__ emb_perm, const float* __restrict__ rbf,
    float v[8])
{
    round_compute(L.ccl, L.r0, L.r1, L.r2, L.r3, L.q0, L.q1, L.q2, L.q3,
                  0, L.degn, L.mb, c, g, wlds, eb_s, emb_perm, v);
    if (L.degn > 16) {                         // rare (P ~ 1%): round 1, slots 16..31
        int ea = 0; float ccl = 0.0f;
        const int slot = 16 + c;
        if (slot < L.degn) {
            const int4 eb = eb_s[L.mb + slot];
            ea  = eb.x;
            ccl = __int_as_float(eb.y);
        }
        const float2* rp2 = (const float2*)(rbf + (size_t)ea * NRBF);
        const float2 r0 = rp2[4 * g],     r1 = rp2[4 * g + 1];
        const float2 r2 = rp2[4 * g + 2], r3 = rp2[4 * g + 3];
        float2 q0 = make_float2(0.f, 0.f), q1 = q0, q2 = q0, q3 = q0;
        if (g < 2) {
            q0 = rp2[16 + 4 * g]; q1 = rp2[17 + 4 * g];
            q2 = rp2[18 + 4 * g]; q3 = rp2[19 + 4 * g];
        } else if (g == 2) {
            q0 = rp2[24];
        }
        round_compute(ccl, r0, r1, r2, r3, q0, q1, q2, q3,
                      16, L.degn, L.mb, c, g, wlds, eb_s, emb_perm, v);
    }
}

__device__ __forceinline__ void finish_node_lds(
    float v[8], int n, int nl, int c, int g, int ocnt,
    const int* __restrict__ ovf, const int* __restrict__ dst,
    const float* __restrict__ dist, const int* __restrict__ src,
    const int* __restrict__ node_type, const float* __restrict__ rbf,
    const unsigned short* __restrict__ W_aug_g,
    const unsigned short* __restrict__ emb_perm,
    unsigned short* __restrict__ cat_s /* [16][264] */)
{
    // Overflow fallback (deg > CAP): essentially never taken, kept for correctness.
    for (int j = 0; j < ocnt; ++j) {
        const int e = ovf[j];
        if (dst[e] != n) continue;
        const float dd  = dist[e];
        const float ccl = 0.5f * (__cosf(dd * (PI_F / CUT)) + 1.0f);
        if (g == 0) {
            const int tau = node_type[src[e]];
            const float* rp = rbf + (size_t)e * NRBF;
            const float ccb16 = bf2f(f2bf(ccl));
            #pragma unroll
            for (int q = 0; q < 8; ++q) {
                const int d = 16 * q + c;
                float s = bf2f(W_aug_g[d * 64 + NRBF]) * ccb16;       // b_e * cc
                for (int k = 0; k < NRBF; ++k)
                    s += bf2f(W_aug_g[d * 64 + k]) * bf2f(f2bf(ccl * rp[k]));
                v[q] += bf2f(f2bf(s * bf2f(emb_perm[tau * DIM + 8 * c + q])));
            }
        }
    }

    #pragma unroll
    for (int q = 0; q < 8; ++q) {
        v[q] += __shfl_xor(v[q], 16);
        v[q] += __shfl_xor(v[q], 32);
    }

    float s0 = v[0], s1 = v[1];
    if (g == 1)      { s0 = v[2]; s1 = v[3]; }
    else if (g == 2) { s0 = v[4]; s1 = v[5]; }
    else if (g == 3) { s0 = v[6]; s1 = v[7]; }
    // xi -> LDS cat rows (k index 128 + dim): identical bits to the old global xi.
    cat_s[nl * 264 + 128 + 32 * g + c]      = f2bf(s0);
    cat_s[nl * 264 + 128 + 32 * g + 16 + c] = f2bf(s1);
}

// ---------------------------------------------------------------------------
// Kernel 2 (FULLY FUSED edge_msg + gather_sum + combine): one kernel, 8 nodes
// per block (NN = 6250 x 8 exactly).
//
// R7 post-mortem: persistent waves hurt (152 us); best gather = R4/R6 geometry.
// The constant-across-rounds hidden ~227 us includes combine_mfma, which
// re-reads the xi this kernel just produced (12.8 MB + a launch). Fusion:
// gather phase (proven structure, eb_s LDS prestage, serial nodes) writes xi
// to an LDS cat tile instead of global; x_nodes is prestaged (bf16) into the
// same tile before the gather loop (latency hidden); one barrier; then each
// wave computes 2 out-dim tiles of out[8][128] = cat[8][256] @ W_c^T + b_c
// with the proven combine fragment mapping and SAME K-accumulation order
// (bit-identical numerics; W_c pre-cast to bf16 W_cb by bucket_prep).
// ---------------------------------------------------------------------------
__global__ __launch_bounds__(256)
void gather_combine(const float* __restrict__ rbf,
                    const int* __restrict__ deg, const int4* __restrict__ ebuf,
                    const unsigned short* __restrict__ W_aug,
                    const unsigned short* __restrict__ emb_perm,
                    const unsigned short* __restrict__ W_cb,
                    const int* __restrict__ ovf, const int* __restrict__ ovf_cnt,
                    const int* __restrict__ dst, const float* __restrict__ dist,
                    const int* __restrict__ src, const int* __restrict__ node_type,
                    const float* __restrict__ x_nodes, const float* __restrict__ b_c,
                    float* __restrict__ out)
{
    __shared__ __align__(16) unsigned short wlds[128 * 72];   // 18 KB W_aug tile
    __shared__ __align__(16) unsigned short cat_s[16 * 264];  // 8.25 KB [x|xi] bf16
    __shared__ int4 eb_s[8 * 32];                             // 4 KB packed slots
    __shared__ int  deg_s[8];

    const int t = threadIdx.x, l = t & 63;
    const int wv = t >> 6;
    const int c = l & 15, g = l >> 4;
    const int n0 = blockIdx.x * 8;

    // ---- block-level prestage (one sync) ----
    {
        eb_s[t] = ebuf[(size_t)n0 * CAP + t];      // 8 nodes x 32 slots, coalesced
        if (t < 8) deg_s[t] = deg[n0 + t];
        #pragma unroll
        for (int i = 0; i < 4; ++i) {
            const int ch = i * 256 + t;            // 1024 x 16-B chunks
            const int row = ch >> 3, f = ch & 7;
            *(int4*)((char*)wlds + row * 144 + f * 16) = ((const int4*)W_aug)[ch];
        }
        // x_nodes -> cat_s rows 0..7, k 0..127 (bf16). 8 nodes x 32 thr x 4 f32.
        const int nl = t >> 5, k0 = (t & 31) * 4;
        const float4 xv = *(const float4*)(x_nodes + (size_t)(n0 + nl) * DIM + k0);
        *(ushort2*)&cat_s[nl * 264 + k0]     = make_ushort2(f2bf(xv.x), f2bf(xv.y));
        *(ushort2*)&cat_s[nl * 264 + k0 + 2] = make_ushort2(f2bf(xv.z), f2bf(xv.w));
    }
    __syncthreads();
    const int ocnt = ovf_cnt[0];

    // ---- gather phase: this wave's 2 nodes, serial (R4-proven) ----
    const int nbase = wv * 2;
    #pragma unroll
    for (int ni = 0; ni < 2; ++ni) {
        const int nl = nbase + ni;
        NodeLoad L;
        issue_node(eb_s, deg_s, rbf, nl, c, g, L);
        float v[8] = {};
        compute_node(L, c, g, wlds, eb_s, emb_perm, rbf, v);
        finish_node_lds(v, n0 + nl, nl, c, g, ocnt, ovf, dst, dist, src,
                        node_type, rbf, W_aug, emb_perm, cat_s);
    }
    __syncthreads();

    // ---- combine phase: wave wv owns out-dim tiles 2wv, 2wv+1 ----
    // A rows = nodes (0..7 real, 8..15 don't-care: D rows are independent).
    f32x4 acc0 = {}, acc1 = {};
    const int t0 = wv * 2, t1 = wv * 2 + 1;
    #pragma unroll
    for (int kc = 0; kc < 8; ++kc) {               // K ascending — proven acc order
        const int ko = kc * 32 + g * 8;
        const short8 af = *(const short8*)&cat_s[c * 264 + ko];
        const short8 b0 = *(const short8*)(W_cb + (size_t)(t0 * 16 + c) * 256 + ko);
        const short8 b1 = *(const short8*)(W_cb + (size_t)(t1 * 16 + c) * 256 + ko);
        acc0 = __builtin_amdgcn_mfma_f32_16x16x32_bf16(af, b0, acc0, 0, 0, 0);
        acc1 = __builtin_amdgcn_mfma_f32_16x16x32_bf16(af, b1, acc1, 0, 0, 0);
    }
    // D: lane (c,g) reg r -> node 4g+r, dim tile*16+c. Only nodes 0..7 real.
    const float bc0 = b_c[t0 * 16 + c];
    const float bc1 = b_c[t1 * 16 + c];
    #pragma unroll
    for (int r = 0; r < 4; ++r) {
        const int node = 4 * g + r;
        if (node < 8) {
            out[(size_t)(n0 + node) * DIM + t0 * 16 + c] = acc0[r] + bc0;
            out[(size_t)(n0 + node) * DIM + t1 * 16 + c] = acc1[r] + bc1;
        }
    }
}

// ---------------------------------------------------------------------------
extern "C" void kernel_launch(void* const* d_in, const int* in_sizes, int n_in,
                              void* d_out, int out_size, void* d_ws, size_t ws_size,
                              hipStream_t stream)
{
    const int*   node_type = (const int*)  d_in[0];
    const float* x_nodes   = (const float*)d_in[1];
    const int*   src       = (const int*)  d_in[2];
    const int*   dst       = (const int*)  d_in[3];
    const float* rbf       = (const float*)d_in[4];
    const float* dist      = (const float*)d_in[5];
    const float* emb       = (const float*)d_in[6];
    const float* W_e       = (const float*)d_in[7];
    const float* b_e       = (const float*)d_in[8];
    const float* W_c       = (const float*)d_in[9];
    const float* b_c       = (const float*)d_in[10];
    float* out = (float*)d_out;

    char* ws = (char*)d_ws;
    int*            deg      = (int*)(ws + OFF_DEG);
    int*            ovf_cnt  = (int*)(ws + OFF_OVFC);
    int4*           ebuf     = (int4*)(ws + OFF_EBUF);
    int*            ovf      = (int*)(ws + OFF_OVF);
    unsigned short* W_aug    = (unsigned short*)(ws + OFF_WAUG);
    unsigned short* emb_perm = (unsigned short*)(ws + OFF_EPERM);
    unsigned short* W_cb     = (unsigned short*)(ws + OFF_WCB);

    hipMemsetAsync(deg, 0, (NN + 1) * sizeof(int), stream);

    bucket_prep<<<(NE + 255) / 256, 256, 0, stream>>>(
        dst, dist, src, node_type, deg, ebuf, ovf, ovf_cnt,
        W_e, b_e, emb, W_c, W_aug, emb_perm, W_cb);

    gather_combine<<<NN / 8, 256, 0, stream>>>(
        rbf, deg, ebuf, W_aug, emb_perm, W_cb,
        ovf, ovf_cnt, dst, dist, src, node_type, x_nodes, b_c, out);
}

// Round 9
// 332.810 us; speedup vs baseline: 1.1579x; 1.0846x over previous
//
#include <hip/hip_runtime.h>
#include <hip/hip_bf16.h>

// Problem constants (fixed by reference setup_inputs)
constexpr int NN   = 50000;    // nodes
constexpr int NE   = 600000;   // edges
constexpr int NRBF = 50;       // rbf features
constexpr int DIM  = 128;      // embedding dim
constexpr float CUT = 5.0f;
constexpr float PI_F = 3.14159265358979323846f;

constexpr int CAP = 32;        // bucket capacity (active degree ~Poisson(9.2); ovf fallback)

// Workspace layout (byte offsets). Total ~28.5 MB.
constexpr size_t OFF_DEG   = 0;                                 // [NN] int
constexpr size_t OFF_OVFC  = (size_t)NN * 4;                    // [1] int (memset covers both)
constexpr size_t OFF_EBUF  = 200960;                            // [NN*CAP] int4 (25.6 MB), 16-B aligned
constexpr size_t OFF_OVF   = OFF_EBUF + (size_t)NN * CAP * 16;  // [NE] int (2.4 MB)
constexpr size_t OFF_WAUG  = OFF_OVF  + (size_t)NE * 4;         // [128*64] bf16 (16 KB)
constexpr size_t OFF_EPERM = OFF_WAUG + 128 * 64 * 2;           // [100*128] bf16 permuted (25.6 KB)
constexpr size_t OFF_WCB   = OFF_EPERM + 100 * 128 * 2;         // [128*256] bf16 W_c (64 KB)

// emb_perm PERMUTED layout: position p holds dim delta(p) = 16*(p&7) + (p>>3).
// Lane c's positions 8c..8c+7 <-> dims {16q + c} = exactly its MFMA-D column across nt.

typedef __attribute__((ext_vector_type(4))) float f32x4;
typedef __attribute__((ext_vector_type(8))) short short8;

__device__ __forceinline__ float bf2f(unsigned short u) {
    return __uint_as_float(((unsigned int)u) << 16);
}
__device__ __forceinline__ unsigned short f2bf(float f) {
    return __bfloat16_as_ushort(__float2bfloat16(f));
}

// ---------------------------------------------------------------------------
// Kernel 1 (bucket_prep v2 — ILP restructure): 4 edges per thread.
// R8 ledger isolated ~150+ us in this kernel; its old form had ONE dependent
// chain per thread (scalar loads -> scattered atomic -> dependent scattered
// store). v2: vectorized int4/float4 loads of dst/dist/src (16-B coalesced),
// node_type gathers hoisted, then FOUR independent atomic->store chains per
// thread. Low tids additionally emit W_aug/emb_perm/W_cb (unchanged).
// ---------------------------------------------------------------------------
__global__ __launch_bounds__(256)
void bucket_prep(const int* __restrict__ dst, const float* __restrict__ dist,
                 const int* __restrict__ src, const int* __restrict__ node_type,
                 int* __restrict__ deg, int4* __restrict__ ebuf,
                 int* __restrict__ ovf, int* __restrict__ ovf_cnt,
                 const float* __restrict__ W_e, const float* __restrict__ b_e,
                 const float* __restrict__ emb, const float* __restrict__ W_c,
                 unsigned short* __restrict__ W_aug, unsigned short* __restrict__ emb_perm,
                 unsigned short* __restrict__ W_cb)
{
    const int tid = blockIdx.x * 256 + threadIdx.x;
    const int e0  = tid * 4;                       // NE % 4 == 0

    if (e0 < NE) {
        const int4   d4 = *(const int4*)(dst + e0);
        const float4 x4 = *(const float4*)(dist + e0);
        const int4   s4 = *(const int4*)(src + e0);
        const int*   dp = (const int*)&d4;
        const float* xp = (const float*)&x4;
        const int*   sp = (const int*)&s4;

        // hoist gathers (independent; L2-hot 200 KB table)
        int tau[4];
        #pragma unroll
        for (int j = 0; j < 4; ++j) tau[j] = node_type[sp[j]];

        #pragma unroll
        for (int j = 0; j < 4; ++j) {
            const float dd = xp[j];
            if (dd < CUT) {
                const float w = 0.5f * (__cosf(dd * (PI_F / CUT)) + 1.0f);
                const int n = dp[j];
                const int pos = atomicAdd(&deg[n], 1);
                if (pos < CAP) {
                    ebuf[(size_t)n * CAP + pos] =
                        make_int4(e0 + j, __float_as_int(w), tau[j], 0);
                } else {
                    ovf[atomicAdd(ovf_cnt, 1)] = e0 + j;
                }
            }
        }
    }

    // small-weight prep, folded in (tids < 53760)
    if (tid < 128 * 64) {
        const int d = tid >> 6, k = tid & 63;
        float v = 0.0f;
        if (k < NRBF)       v = W_e[d * NRBF + k];
        else if (k == NRBF) v = b_e[d];
        W_aug[tid] = f2bf(v);
    } else if (tid < 128 * 64 + 100 * 128) {
        const int i = tid - 128 * 64;
        const int tau = i >> 7, p = i & 127;
        const int d = 16 * (p & 7) + (p >> 3);
        emb_perm[i] = f2bf(emb[tau * DIM + d]);
    } else if (tid < 128 * 64 + 100 * 128 + 128 * 256) {
        const int i = tid - (128 * 64 + 100 * 128);
        W_cb[i] = f2bf(W_c[i]);                    // row-major [128][256], same index
    }
}

// ---------------------------------------------------------------------------
// Fused gather helpers. Arithmetic is BIT-IDENTICAL to the proven R4/R6 path.
// ---------------------------------------------------------------------------
struct NodeLoad {
    float2 r0, r1, r2, r3, q0, q1, q2, q3;   // raw rbf float2s for round 0
    float  ccl;
    int    degn;
    int    mb;
};

__device__ __forceinline__ void issue_node(const int4* __restrict__ eb_s,
                                           const int* __restrict__ deg_s,
                                           const float* __restrict__ rbf,
                                           int nl, int c, int g, NodeLoad& L)
{
    const int dn = deg_s[nl];
    L.degn = dn < CAP ? dn : CAP;
    L.mb   = nl * 32;
    int ea = 0; L.ccl = 0.0f;
    if (c < L.degn) {                         // round-0 slot = c
        const int4 eb = eb_s[L.mb + c];
        ea    = eb.x;
        L.ccl = __int_as_float(eb.y);
    }
    const float2* rp2 = (const float2*)(rbf + (size_t)ea * NRBF);  // ea=0 inactive: safe
    L.r0 = rp2[4 * g];     L.r1 = rp2[4 * g + 1];
    L.r2 = rp2[4 * g + 2]; L.r3 = rp2[4 * g + 3];
    L.q0 = make_float2(0.f, 0.f); L.q1 = L.q0; L.q2 = L.q0; L.q3 = L.q0;
    if (g < 2) {
        L.q0 = rp2[16 + 4 * g]; L.q1 = rp2[17 + 4 * g];
        L.q2 = rp2[18 + 4 * g]; L.q3 = rp2[19 + 4 * g];
    } else if (g == 2) {
        L.q0 = rp2[24];                        // k48,k49
    }
}

__device__ __forceinline__ void round_compute(
    float ccl, float2 r0, float2 r1, float2 r2, float2 r3,
    float2 q0, float2 q1, float2 q2, float2 q3,
    int j0, int degn, int mb, int c, int g,
    const unsigned short* __restrict__ wlds, const int4* __restrict__ eb_s,
    const unsigned short* __restrict__ emb_perm, float v[8])
{
    short8 a0, a1;
    a0[0] = (short)f2bf(ccl * r0.x); a0[1] = (short)f2bf(ccl * r0.y);
    a0[2] = (short)f2bf(ccl * r1.x); a0[3] = (short)f2bf(ccl * r1.y);
    a0[4] = (short)f2bf(ccl * r2.x); a0[5] = (short)f2bf(ccl * r2.y);
    a0[6] = (short)f2bf(ccl * r3.x); a0[7] = (short)f2bf(ccl * r3.y);
    a1[0] = (short)f2bf(ccl * q0.x); a1[1] = (short)f2bf(ccl * q0.y);
    a1[2] = (short)f2bf(ccl * q1.x); a1[3] = (short)f2bf(ccl * q1.y);
    a1[4] = (short)f2bf(ccl * q2.x); a1[5] = (short)f2bf(ccl * q2.y);
    a1[6] = (short)f2bf(ccl * q3.x); a1[7] = (short)f2bf(ccl * q3.y);
    if (g == 2) {                              // k50 = cc (b_e hook), k51+ = 0
        a1[2] = (short)f2bf(ccl);
        a1[3] = 0; a1[4] = 0; a1[5] = 0; a1[6] = 0; a1[7] = 0;
    }

    f32x4 acc[8] = {};
    #pragma unroll
    for (int nt = 0; nt < 8; ++nt) {
        const short8 bf0 = *(const short8*)((const char*)wlds + (nt * 16 + c) * 144 + g * 16);
        acc[nt] = __builtin_amdgcn_mfma_f32_16x16x32_bf16(a0, bf0, acc[nt], 0, 0, 0);
    }
    #pragma unroll
    for (int nt = 0; nt < 8; ++nt) {
        const short8 bf1 = *(const short8*)((const char*)wlds + (nt * 16 + c) * 144 + (4 + g) * 16);
        acc[nt] = __builtin_amdgcn_mfma_f32_16x16x32_bf16(a1, bf1, acc[nt], 0, 0, 0);
    }

    #pragma unroll
    for (int r = 0; r < 4; ++r) {
        const int jr = j0 + 4 * g + r;
        if (jr < degn) {
            const int rw = ((const int*)&eb_s[mb + jr])[2];      // tau
            const int4 em = *(const int4*)(emb_perm + rw * DIM + 8 * c);
            const unsigned int* ep = (const unsigned int*)&em;
            #pragma unroll
            for (int q = 0; q < 4; ++q) {
                const float m0 = bf2f((unsigned short)(ep[q] & 0xffff));
                const float m1 = bf2f((unsigned short)(ep[q] >> 16));
                v[2 * q]     += bf2f(f2bf(acc[2 * q][r]     * m0));   // bf16-round: bit-
                v[2 * q + 1] += bf2f(f2bf(acc[2 * q + 1][r] * m1));   // identical to msg path
            }
        }
    }
}

__device__ __forceinline__ void compute_node(
    const NodeLoad& L, int c, int g,
    const unsigned short* __restrict__ wlds, const int4* __restrict__ eb_s,
    const unsigned short* __restrict__ emb_perm, const float* __restrict__ rbf,
    float v[8])
{
    round_compute(L.ccl, L.r0, L.r1, L.r2, L.r3, L.q0, L.q1, L.q2, L.q3,
                  0, L.degn, L.mb, c, g, wlds, eb_s, emb_perm, v);
    if (L.degn > 16) {                         // rare (P ~ 1%): round 1, slots 16..31
        int ea = 0; float ccl = 0.0f;
        const int slot = 16 + c;
        if (slot < L.degn) {
            const int4 eb = eb_s[L.mb + slot];
            ea  = eb.x;
            ccl = __int_as_float(eb.y);
        }
        const float2* rp2 = (const float2*)(rbf + (size_t)ea * NRBF);
        const float2 r0 = rp2[4 * g],     r1 = rp2[4 * g + 1];
        const float2 r2 = rp2[4 * g + 2], r3 = rp2[4 * g + 3];
        float2 q0 = make_float2(0.f, 0.f), q1 = q0, q2 = q0, q3 = q0;
        if (g < 2) {
            q0 = rp2[16 + 4 * g]; q1 = rp2[17 + 4 * g];
            q2 = rp2[18 + 4 * g]; q3 = rp2[19 + 4 * g];
        } else if (g == 2) {
            q0 = rp2[24];
        }
        round_compute(ccl, r0, r1, r2, r3, q0, q1, q2, q3,
                      16, L.degn, L.mb, c, g, wlds, eb_s, emb_perm, v);
    }
}

__device__ __forceinline__ void finish_node_lds(
    float v[8], int n, int nl, int c, int g, int ocnt,
    const int* __restrict__ ovf, const int* __restrict__ dst,
    const float* __restrict__ dist, const int* __restrict__ src,
    const int* __restrict__ node_type, const float* __restrict__ rbf,
    const unsigned short* __restrict__ W_aug_g,
    const unsigned short* __restrict__ emb_perm,
    unsigned short* __restrict__ cat_s /* [16][264] */)
{
    // Overflow fallback (deg > CAP): essentially never taken, kept for correctness.
    for (int j = 0; j < ocnt; ++j) {
        const int e = ovf[j];
        if (dst[e] != n) continue;
        const float dd  = dist[e];
        const float ccl = 0.5f * (__cosf(dd * (PI_F / CUT)) + 1.0f);
        if (g == 0) {
            const int tau = node_type[src[e]];
            const float* rp = rbf + (size_t)e * NRBF;
            const float ccb16 = bf2f(f2bf(ccl));
            #pragma unroll
            for (int q = 0; q < 8; ++q) {
                const int d = 16 * q + c;
                float s = bf2f(W_aug_g[d * 64 + NRBF]) * ccb16;       // b_e * cc
                for (int k = 0; k < NRBF; ++k)
                    s += bf2f(W_aug_g[d * 64 + k]) * bf2f(f2bf(ccl * rp[k]));
                v[q] += bf2f(f2bf(s * bf2f(emb_perm[tau * DIM + 8 * c + q])));
            }
        }
    }

    #pragma unroll
    for (int q = 0; q < 8; ++q) {
        v[q] += __shfl_xor(v[q], 16);
        v[q] += __shfl_xor(v[q], 32);
    }

    float s0 = v[0], s1 = v[1];
    if (g == 1)      { s0 = v[2]; s1 = v[3]; }
    else if (g == 2) { s0 = v[4]; s1 = v[5]; }
    else if (g == 3) { s0 = v[6]; s1 = v[7]; }
    // xi -> LDS cat rows (k index 128 + dim): identical bits to the old global xi.
    cat_s[nl * 264 + 128 + 32 * g + c]      = f2bf(s0);
    cat_s[nl * 264 + 128 + 32 * g + 16 + c] = f2bf(s1);
}

// ---------------------------------------------------------------------------
// Kernel 2 (FULLY FUSED edge_msg + gather_sum + combine, v2 — 16 nodes/block).
//
// R8 post-mortem: fusion correct at 164 us (gather ~128 + combine ~36), but
// the combine phase wasted half its MFMA rows (8 real nodes in a 16-row A) and
// each block paid the 18-KB wlds stage for only 8 nodes. v2: 16 nodes/block
// (NN = 3125 x 16 exactly): wlds stage amortized 2x, combine A-rows ALL real
// (per-node combine MFMA halves), gather runs 4 serial nodes/wave (proven
// structure). Fragment mappings and K-order unchanged -> bit-identical.
// ---------------------------------------------------------------------------
__global__ __launch_bounds__(256)
void gather_combine(const float* __restrict__ rbf,
                    const int* __restrict__ deg, const int4* __restrict__ ebuf,
                    const unsigned short* __restrict__ W_aug,
                    const unsigned short* __restrict__ emb_perm,
                    const unsigned short* __restrict__ W_cb,
                    const int* __restrict__ ovf, const int* __restrict__ ovf_cnt,
                    const int* __restrict__ dst, const float* __restrict__ dist,
                    const int* __restrict__ src, const int* __restrict__ node_type,
                    const float* __restrict__ x_nodes, const float* __restrict__ b_c,
                    float* __restrict__ out)
{
    __shared__ __align__(16) unsigned short wlds[128 * 72];   // 18 KB W_aug tile
    __shared__ __align__(16) unsigned short cat_s[16 * 264];  // 8.25 KB [x|xi] bf16
    __shared__ int4 eb_s[16 * 32];                            // 8 KB packed slots
    __shared__ int  deg_s[16];

    const int t = threadIdx.x, l = t & 63;
    const int wv = t >> 6;
    const int c = l & 15, g = l >> 4;
    const int n0 = blockIdx.x * 16;

    // ---- block-level prestage (one sync) ----
    {
        eb_s[t]       = ebuf[(size_t)n0 * CAP + t];        // 16 nodes x 32 slots,
        eb_s[256 + t] = ebuf[(size_t)n0 * CAP + 256 + t];  // coalesced
        if (t < 16) deg_s[t] = deg[n0 + t];
        #pragma unroll
        for (int i = 0; i < 4; ++i) {
            const int ch = i * 256 + t;            // 1024 x 16-B chunks
            const int row = ch >> 3, f = ch & 7;
            *(int4*)((char*)wlds + row * 144 + f * 16) = ((const int4*)W_aug)[ch];
        }
        // x_nodes -> cat_s rows 0..15, k 0..127 (bf16). 16 thr/node x 8 f32 each.
        const int nl = t >> 4, k0 = (t & 15) * 8;
        const float4 xv0 = *(const float4*)(x_nodes + (size_t)(n0 + nl) * DIM + k0);
        const float4 xv1 = *(const float4*)(x_nodes + (size_t)(n0 + nl) * DIM + k0 + 4);
        unsigned short* dp = &cat_s[nl * 264 + k0];
        *(ushort2*)&dp[0] = make_ushort2(f2bf(xv0.x), f2bf(xv0.y));
        *(ushort2*)&dp[2] = make_ushort2(f2bf(xv0.z), f2bf(xv0.w));
        *(ushort2*)&dp[4] = make_ushort2(f2bf(xv1.x), f2bf(xv1.y));
        *(ushort2*)&dp[6] = make_ushort2(f2bf(xv1.z), f2bf(xv1.w));
    }
    __syncthreads();
    const int ocnt = ovf_cnt[0];

    // ---- gather phase: this wave's 4 nodes, serial (proven structure) ----
    const int nbase = wv * 4;
    #pragma unroll
    for (int ni = 0; ni < 4; ++ni) {
        const int nl = nbase + ni;
        NodeLoad L;
        issue_node(eb_s, deg_s, rbf, nl, c, g, L);
        float v[8] = {};
        compute_node(L, c, g, wlds, eb_s, emb_perm, rbf, v);
        finish_node_lds(v, n0 + nl, nl, c, g, ocnt, ovf, dst, dist, src,
                        node_type, rbf, W_aug, emb_perm, cat_s);
    }
    __syncthreads();

    // ---- combine phase: wave wv owns out-dim tiles 2wv, 2wv+1; A rows = 16
    // real nodes (no waste). Proven fragment mapping, K ascending. ----
    f32x4 acc0 = {}, acc1 = {};
    const int t0 = wv * 2, t1 = wv * 2 + 1;
    #pragma unroll
    for (int kc = 0; kc < 8; ++kc) {
        const int ko = kc * 32 + g * 8;
        const short8 af = *(const short8*)&cat_s[c * 264 + ko];
        const short8 b0 = *(const short8*)(W_cb + (size_t)(t0 * 16 + c) * 256 + ko);
        const short8 b1 = *(const short8*)(W_cb + (size_t)(t1 * 16 + c) * 256 + ko);
        acc0 = __builtin_amdgcn_mfma_f32_16x16x32_bf16(af, b0, acc0, 0, 0, 0);
        acc1 = __builtin_amdgcn_mfma_f32_16x16x32_bf16(af, b1, acc1, 0, 0, 0);
    }
    // D: lane (c,g) reg r -> node 4g+r (all 16 real), dim tile*16+c.
    const float bc0 = b_c[t0 * 16 + c];
    const float bc1 = b_c[t1 * 16 + c];
    #pragma unroll
    for (int r = 0; r < 4; ++r) {
        const int node = 4 * g + r;
        out[(size_t)(n0 + node) * DIM + t0 * 16 + c] = acc0[r] + bc0;
        out[(size_t)(n0 + node) * DIM + t1 * 16 + c] = acc1[r] + bc1;
    }
}

// ---------------------------------------------------------------------------
extern "C" void kernel_launch(void* const* d_in, const int* in_sizes, int n_in,
                              void* d_out, int out_size, void* d_ws, size_t ws_size,
                              hipStream_t stream)
{
    const int*   node_type = (const int*)  d_in[0];
    const float* x_nodes   = (const float*)d_in[1];
    const int*   src       = (const int*)  d_in[2];
    const int*   dst       = (const int*)  d_in[3];
    const float* rbf       = (const float*)d_in[4];
    const float* dist      = (const float*)d_in[5];
    const float* emb       = (const float*)d_in[6];
    const float* W_e       = (const float*)d_in[7];
    const float* b_e       = (const float*)d_in[8];
    const float* W_c       = (const float*)d_in[9];
    const float* b_c       = (const float*)d_in[10];
    float* out = (float*)d_out;

    char* ws = (char*)d_ws;
    int*            deg      = (int*)(ws + OFF_DEG);
    int*            ovf_cnt  = (int*)(ws + OFF_OVFC);
    int4*           ebuf     = (int4*)(ws + OFF_EBUF);
    int*            ovf      = (int*)(ws + OFF_OVF);
    unsigned short* W_aug    = (unsigned short*)(ws + OFF_WAUG);
    unsigned short* emb_perm = (unsigned short*)(ws + OFF_EPERM);
    unsigned short* W_cb     = (unsigned short*)(ws + OFF_WCB);

    hipMemsetAsync(deg, 0, (NN + 1) * sizeof(int), stream);

    bucket_prep<<<(NE / 4 + 255) / 256, 256, 0, stream>>>(
        dst, dist, src, node_type, deg, ebuf, ovf, ovf_cnt,
        W_e, b_e, emb, W_c, W_aug, emb_perm, W_cb);

    gather_combine<<<NN / 16, 256, 0, stream>>>(
        rbf, deg, ebuf, W_aug, emb_perm, W_cb,
        ovf, ovf_cnt, dst, dist, src, node_type, x_nodes, b_c, out);
}